// Round 6
// baseline (72.383 us; speedup 1.0000x reference)
//
#include <hip/hip_runtime.h>

typedef __attribute__((ext_vector_type(8))) short short8;
typedef __attribute__((ext_vector_type(4))) float f32x4;

constexpr int BATCH = 4;
constexpr int SEQ   = 512;
constexpr int DM    = 256;

#define MFMA(a,b,c) __builtin_amdgcn_mfma_f32_16x16x32_bf16((a),(b),(c),0,0,0)

// ---------------------------------------------------------------------------
__device__ __forceinline__ unsigned short bf16h(float x) {
    unsigned u = __float_as_uint(x);
    return (unsigned short)((u + 0x7FFF + ((u >> 16) & 1)) >> 16);  // RNE
}
__device__ __forceinline__ float bf16f(unsigned short h) {
    return __uint_as_float(((unsigned)h) << 16);
}
__device__ __forceinline__ float exp2x_clamped(float x) {
    x = fminf(5.0f, fmaxf(-5.0f, x));
    return __builtin_amdgcn_exp2f(x * 2.8853900817779268f); // exp(2x)
}
__device__ __forceinline__ void cvt8(const float* s, int4& h, int4& l) {
    unsigned hw[8], lw[8];
    #pragma unroll
    for (int j = 0; j < 8; ++j) {
        unsigned short hb = bf16h(s[j]);
        hw[j] = hb;
        lw[j] = bf16h(s[j] - bf16f(hb));
    }
    h.x = (int)(hw[0] | (hw[1] << 16)); h.y = (int)(hw[2] | (hw[3] << 16));
    h.z = (int)(hw[4] | (hw[5] << 16)); h.w = (int)(hw[6] | (hw[7] << 16));
    l.x = (int)(lw[0] | (lw[1] << 16)); l.y = (int)(lw[2] | (lw[3] << 16));
    l.z = (int)(lw[4] | (lw[5] << 16)); l.w = (int)(lw[6] | (lw[7] << 16));
}

// ---------------------------------------------------------------------------
// f32 -> bf16 hi/lo pre-conversion, WEIGHTS ONLY (q/k/v converted inline in proj).
__global__ __launch_bounds__(256) void conv_w(
    const float* __restrict__ Wq, const float* __restrict__ Wk,
    const float* __restrict__ Wv, const float* __restrict__ Wo,
    ushort* Wqh, ushort* Wql, ushort* Wkh, ushort* Wkl,
    ushort* Wvh, ushort* Wvl, ushort* Woh, ushort* Wol)
{
    const float* s; ushort* h; ushort* l;
    switch (blockIdx.y) {
        case 0: s = Wq; h = Wqh; l = Wql; break;
        case 1: s = Wk; h = Wkh; l = Wkl; break;
        case 2: s = Wv; h = Wvh; l = Wvl; break;
        default:s = Wo; h = Woh; l = Wol; break;
    }
    int idx = (blockIdx.x * 256 + threadIdx.x) * 8;   // 32 blocks x 2048 = 65536
    float4 f0 = *(const float4*)(s + idx);
    float4 f1 = *(const float4*)(s + idx + 4);
    float xs[8] = {f0.x, f0.y, f0.z, f0.w, f1.x, f1.y, f1.z, f1.w};
    int4 ph, pl;
    cvt8(xs, ph, pl);
    *(int4*)&h[idx] = ph;
    *(int4*)&l[idx] = pl;
}

// ---------------------------------------------------------------------------
// MFMA GEMM core: C[m][n] = sum_k A[m][k]*B[n][k] over K=256 (4 iters of BK=64).
// f32 emulated as bf16 hi/lo, 3 MFMA passes (hh + hl + lh).
// Tile 64x64, 4 waves (2x2), LDS in frag-linear chunk order (no swizzle needed).
// EPI: 0 = bias+exp (f32 C), 1 = bias + bf16 h/l transposed out (vpT),
//      2 = plain f32 C, 3 = bias (f32 C).
// ASRC: 0 = A from bf16 h/l arrays; 1 = A from f32 (inline cvt);
//       2 = A from sum of two f32 arrays (inline cvt).
template<int EPI, int ASRC>
__device__ __forceinline__ void mfma_core(
    const ushort* __restrict__ Ah, const ushort* __restrict__ Al,
    const float*  __restrict__ A0, const float*  __restrict__ A1, long ldA,
    const ushort* __restrict__ Bh, const ushort* __restrict__ Bl, long ldB,
    float* __restrict__ C, long ldC, const float* __restrict__ bias,
    ushort* __restrict__ Th, ushort* __restrict__ Tl, long ldT)
{
    __shared__ short lds[16384];   // 4 regions x 512 chunks x 8 shorts = 32 KB
    const int tid = threadIdx.x;
    const int i0 = tid, i1 = tid + 256;
    const int r0 = ((i0 >> 7) << 4) | (i0 & 15), r1 = ((i1 >> 7) << 4) | (i1 & 15);
    const int c0 = ((i0 >> 4) & 7) * 8,          c1 = ((i1 >> 4) & 7) * 8;
    const long a0o = (long)r0 * ldA + c0, a1o = (long)r1 * ldA + c1;
    const long b0o = (long)r0 * ldB + c0, b1o = (long)r1 * ldB + c1;

    int4 rah0, rah1, ral0, ral1, rbh0, rbh1, rbl0, rbl1;
    float4 fa00, fa01, fa10, fa11, fb00, fb01, fb10, fb11;

    auto issue_loads = [&](int it) {
        long off = (long)it * 64;
        if constexpr (ASRC != 0) {
            fa00 = *(const float4*)(A0 + a0o + off); fa01 = *(const float4*)(A0 + a0o + off + 4);
            fa10 = *(const float4*)(A0 + a1o + off); fa11 = *(const float4*)(A0 + a1o + off + 4);
            if constexpr (ASRC == 2) {
                fb00 = *(const float4*)(A1 + a0o + off); fb01 = *(const float4*)(A1 + a0o + off + 4);
                fb10 = *(const float4*)(A1 + a1o + off); fb11 = *(const float4*)(A1 + a1o + off + 4);
            }
        } else {
            rah0 = *(const int4*)(Ah + a0o + off); rah1 = *(const int4*)(Ah + a1o + off);
            ral0 = *(const int4*)(Al + a0o + off); ral1 = *(const int4*)(Al + a1o + off);
        }
        rbh0 = *(const int4*)(Bh + b0o + off); rbh1 = *(const int4*)(Bh + b1o + off);
        rbl0 = *(const int4*)(Bl + b0o + off); rbl1 = *(const int4*)(Bl + b1o + off);
    };
    auto write_lds = [&]() {
        if constexpr (ASRC != 0) {
            float s0[8], s1[8];
            if constexpr (ASRC == 2) {
                s0[0]=fa00.x+fb00.x; s0[1]=fa00.y+fb00.y; s0[2]=fa00.z+fb00.z; s0[3]=fa00.w+fb00.w;
                s0[4]=fa01.x+fb01.x; s0[5]=fa01.y+fb01.y; s0[6]=fa01.z+fb01.z; s0[7]=fa01.w+fb01.w;
                s1[0]=fa10.x+fb10.x; s1[1]=fa10.y+fb10.y; s1[2]=fa10.z+fb10.z; s1[3]=fa10.w+fb10.w;
                s1[4]=fa11.x+fb11.x; s1[5]=fa11.y+fb11.y; s1[6]=fa11.z+fb11.z; s1[7]=fa11.w+fb11.w;
            } else {
                s0[0]=fa00.x; s0[1]=fa00.y; s0[2]=fa00.z; s0[3]=fa00.w;
                s0[4]=fa01.x; s0[5]=fa01.y; s0[6]=fa01.z; s0[7]=fa01.w;
                s1[0]=fa10.x; s1[1]=fa10.y; s1[2]=fa10.z; s1[3]=fa10.w;
                s1[4]=fa11.x; s1[5]=fa11.y; s1[6]=fa11.z; s1[7]=fa11.w;
            }
            int4 h, l2;
            cvt8(s0, h, l2);
            *(int4*)&lds[i0 * 8] = h; *(int4*)&lds[4096 + i0 * 8] = l2;
            cvt8(s1, h, l2);
            *(int4*)&lds[i1 * 8] = h; *(int4*)&lds[4096 + i1 * 8] = l2;
        } else {
            *(int4*)&lds[i0 * 8] = rah0;        *(int4*)&lds[i1 * 8] = rah1;
            *(int4*)&lds[4096 + i0 * 8] = ral0; *(int4*)&lds[4096 + i1 * 8] = ral1;
        }
        *(int4*)&lds[8192  + i0 * 8] = rbh0; *(int4*)&lds[8192  + i1 * 8] = rbh1;
        *(int4*)&lds[12288 + i0 * 8] = rbl0; *(int4*)&lds[12288 + i1 * 8] = rbl1;
    };

    const int l = tid & 63, w = tid >> 6;
    const int ms = (w >> 1) * 2, ns = (w & 1) * 2;
    f32x4 acc00 = {0,0,0,0}, acc01 = {0,0,0,0}, acc10 = {0,0,0,0}, acc11 = {0,0,0,0};

    issue_loads(0);
    for (int it = 0; it < 4; ++it) {
        write_lds();
        __syncthreads();
        if (it < 3) issue_loads(it + 1);
        const int lo = l * 8;
        #pragma unroll
        for (int ks = 0; ks < 2; ++ks) {
            short8 a0h = *(const short8*)&lds[((ms    ) * 2 + ks) * 512 + lo];
            short8 a1h = *(const short8*)&lds[((ms + 1) * 2 + ks) * 512 + lo];
            short8 a0l = *(const short8*)&lds[4096 + ((ms    ) * 2 + ks) * 512 + lo];
            short8 a1l = *(const short8*)&lds[4096 + ((ms + 1) * 2 + ks) * 512 + lo];
            short8 b0h = *(const short8*)&lds[8192 + ((ns    ) * 2 + ks) * 512 + lo];
            short8 b1h = *(const short8*)&lds[8192 + ((ns + 1) * 2 + ks) * 512 + lo];
            short8 b0l = *(const short8*)&lds[12288 + ((ns    ) * 2 + ks) * 512 + lo];
            short8 b1l = *(const short8*)&lds[12288 + ((ns + 1) * 2 + ks) * 512 + lo];
            acc00 = MFMA(a0h, b0h, acc00); acc00 = MFMA(a0h, b0l, acc00); acc00 = MFMA(a0l, b0h, acc00);
            acc01 = MFMA(a0h, b1h, acc01); acc01 = MFMA(a0h, b1l, acc01); acc01 = MFMA(a0l, b1h, acc01);
            acc10 = MFMA(a1h, b0h, acc10); acc10 = MFMA(a1h, b0l, acc10); acc10 = MFMA(a1l, b0h, acc10);
            acc11 = MFMA(a1h, b1h, acc11); acc11 = MFMA(a1h, b1l, acc11); acc11 = MFMA(a1l, b1h, acc11);
        }
        __syncthreads();
    }

    auto epi = [&](int i, int j, f32x4 a) {
        const int n  = (ns + j) * 16 + (l & 15);
        const int mb = (ms + i) * 16 + (l >> 4) * 4;
        if constexpr (EPI == 1) {
            float bb = bias[n];
            float x0 = a.x + bb, x1 = a.y + bb, x2 = a.z + bb, x3 = a.w + bb;
            unsigned short h0 = bf16h(x0), h1 = bf16h(x1), h2 = bf16h(x2), h3 = bf16h(x3);
            int2 ph, pl;
            ph.x = (int)(h0 | ((unsigned)h1 << 16));
            ph.y = (int)(h2 | ((unsigned)h3 << 16));
            pl.x = (int)(bf16h(x0 - bf16f(h0)) | ((unsigned)bf16h(x1 - bf16f(h1)) << 16));
            pl.y = (int)(bf16h(x2 - bf16f(h2)) | ((unsigned)bf16h(x3 - bf16f(h3)) << 16));
            *(int2*)&Th[(long)n * ldT + mb] = ph;
            *(int2*)&Tl[(long)n * ldT + mb] = pl;
        } else {
            float bb = (EPI == 2) ? 0.f : bias[n];
            float xs[4] = {a.x, a.y, a.z, a.w};
            #pragma unroll
            for (int r = 0; r < 4; ++r) {
                float x = xs[r] + bb;
                if constexpr (EPI == 0) x = exp2x_clamped(x);
                C[(long)(mb + r) * ldC + n] = x;
            }
        }
    };
    epi(0, 0, acc00); epi(0, 1, acc01); epi(1, 0, acc10); epi(1, 1, acc11);
}

// ---------------------------------------------------------------------------
// z=0: Eq=exp(2*(q@Wq^T+bq)); z=1: Ek likewise; z=2: vpT h/l (transposed bf16).
// A staged directly from f32 inputs (inline hi/lo conversion).
__global__ __launch_bounds__(256) void proj_mfma(
    const float* __restrict__ q, const float* __restrict__ k, const float* __restrict__ v,
    const ushort* Wqh, const ushort* Wql, const ushort* Wkh, const ushort* Wkl,
    const ushort* Wvh, const ushort* Wvl,
    const float* bq, const float* bk, const float* bv,
    float* Eq, float* Ek, ushort* vpTh, ushort* vpTl)
{
    const int z = blockIdx.z;
    const long m0 = blockIdx.x * 64, n0 = blockIdx.y * 64;
    const float* A; const ushort *Bh, *Bl; const float* bias;
    if (z == 0)      { A = q; Bh = Wqh; Bl = Wql; bias = bq; }
    else if (z == 1) { A = k; Bh = Wkh; Bl = Wkl; bias = bk; }
    else             { A = v; Bh = Wvh; Bl = Wvl; bias = bv; }
    A += m0 * 256; Bh += n0 * 256; Bl += n0 * 256; bias += n0;
    if (z < 2) {
        float* C = (z ? Ek : Eq) + m0 * 256 + n0;
        mfma_core<0, 1>(nullptr, nullptr, A, nullptr, 256, Bh, Bl, 256,
                        C, 256, bias, nullptr, nullptr, 0);
    } else {
        mfma_core<1, 1>(nullptr, nullptr, A, nullptr, 256, Bh, Bl, 256,
                        nullptr, 0, bias,
                        vpTh + n0 * 2048 + m0, vpTl + n0 * 2048 + m0, 2048);
    }
}

// attended partials: z = b*2+h, K-half h of attn[b] @ vp[b] -> att0/att1
__global__ __launch_bounds__(256) void attnv_mfma(
    const ushort* attn_h, const ushort* attn_l,
    const ushort* vpTh, const ushort* vpTl, float* att0, float* att1)
{
    const int z = blockIdx.z, b = z >> 1, h = z & 1;
    const long m0 = blockIdx.x * 64, n0 = blockIdx.y * 64;
    const long arow = (long)b * SEQ + m0;
    const ushort* Ah = attn_h + arow * SEQ + h * 256;
    const ushort* Al = attn_l + arow * SEQ + h * 256;
    const ushort* Bh = vpTh + n0 * 2048 + (long)b * SEQ + h * 256;
    const ushort* Bl = vpTl + n0 * 2048 + (long)b * SEQ + h * 256;
    float* C = (h ? att1 : att0) + arow * DM + n0;
    mfma_core<2, 0>(Ah, Al, nullptr, nullptr, SEQ, Bh, Bl, 2048,
                    C, DM, nullptr, nullptr, nullptr, 0);
}

// out = (att0+att1) @ Wo^T + bo
__global__ __launch_bounds__(256) void out_mfma(
    const float* att0, const float* att1,
    const ushort* Woh, const ushort* Wol, const float* bo, float* out)
{
    const long m0 = blockIdx.x * 64, n0 = blockIdx.y * 64;
    mfma_core<3, 2>(nullptr, nullptr, att0 + m0 * 256, att1 + m0 * 256, 256,
                    Woh + n0 * 256, Wol + n0 * 256, 256,
                    out + m0 * 256 + n0, 256, bo + n0, nullptr, nullptr, 0);
}

// ---------------------------------------------------------------------------
// score(q,k) = const - 2*sum_d w_d/(1+Eq_d*Ek_d); 4 d's share ONE rcp:
//   w0/x0+w1/x1+w2/x2+w3/x3 = ((w0*x1+w1*x0)*x2*x3 + (w2*x3+w3*x2)*x0*x1)
//                              * rcp(x0*x1*x2*x3)
// 64x64 tile, 4x4 microtile (2B LDS/elem-d), d-split x4 across blocks:
// grid 8x8x16 = 1024 blocks = 4 blocks/CU = 4 waves/SIMD (round-4 proven config).
__global__ __launch_bounds__(256) void scores_kernel(
    const float* __restrict__ Eq, const float* __restrict__ Ek,
    const float* __restrict__ Ws, float* __restrict__ part)
{
    __shared__ __align__(16) float qL[64][68];
    __shared__ __align__(16) float kL[64][68];
    const int z = blockIdx.z;          // b*4 + dchunk
    const int b = z >> 2, c = z & 3;
    const int c0 = c * 64;
    const int q0 = blockIdx.x * 64, k0 = blockIdx.y * 64;
    const int tid = threadIdx.x;
    const int qi = tid >> 4, ki = tid & 15;
    const float* Eqb = Eq + ((long)b * SEQ + q0) * DM + c0;
    const float* Ekb = Ek + ((long)b * SEQ + k0) * DM + c0;

    #pragma unroll
    for (int i = 0; i < 4; ++i) {      // 64 rows x 64 floats per side
        int f = i * 256 + tid;
        int r = f >> 4, col = (f & 15) << 2;
        *(float4*)&qL[r][col] = *(const float4*)(Eqb + (long)r * DM + col);
        *(float4*)&kL[r][col] = *(const float4*)(Ekb + (long)r * DM + col);
    }
    __syncthreads();

    float acc[4][4] = {};
    #pragma unroll 2
    for (int d = 0; d < 64; d += 4) {
        float4 w4 = *(const float4*)(Ws + c0 + d);     // uniform -> s_load
        float4 av[4], bv[4];
        #pragma unroll
        for (int i = 0; i < 4; ++i) av[i] = *(const float4*)&qL[qi + 16 * i][d];
        #pragma unroll
        for (int j = 0; j < 4; ++j) bv[j] = *(const float4*)&kL[ki + 16 * j][d];
        #pragma unroll
        for (int i = 0; i < 4; ++i)
            #pragma unroll
            for (int j = 0; j < 4; ++j) {
                float xp = fmaf(av[i].x, bv[j].x, 1.0f);
                float yp = fmaf(av[i].y, bv[j].y, 1.0f);
                float zp = fmaf(av[i].z, bv[j].z, 1.0f);
                float wp = fmaf(av[i].w, bv[j].w, 1.0f);
                float xy = xp * yp, zw = zp * wp;
                float n1 = fmaf(w4.x, yp, w4.y * xp);
                float n2 = fmaf(w4.z, wp, w4.w * zp);
                float num = fmaf(n1, zw, n2 * xy);
                acc[i][j] = fmaf(num, __builtin_amdgcn_rcpf(xy * zw), acc[i][j]);
            }
    }

    float* pb = part + (long)c * (BATCH * SEQ * SEQ) + (long)b * SEQ * SEQ;
    #pragma unroll
    for (int i = 0; i < 4; ++i) {
        float* row = pb + (long)(q0 + qi + 16 * i) * SEQ + k0 + ki;
        #pragma unroll
        for (int j = 0; j < 4; ++j) row[16 * j] = acc[i][j];
    }
}

// ---------------------------------------------------------------------------
// Combine 4 d-partials, scale -2, softmax rows of 512; emit f32 attn (output)
// and bf16 hi/lo attn for the MFMA attnv stage.
__global__ __launch_bounds__(256) void softmax_kernel(
    const float* __restrict__ part, float* __restrict__ attn,
    ushort* __restrict__ attn_h, ushort* __restrict__ attn_l)
{
    __shared__ float red[8];
    const int tid = threadIdx.x;
    const long row = blockIdx.x;
    constexpr long PS = (long)BATCH * SEQ * SEQ;
    const float* p = part + row * SEQ + tid * 2;
    float2 v0 = *(const float2*)(p);
    float2 v1 = *(const float2*)(p + PS);
    float2 v2 = *(const float2*)(p + 2 * PS);
    float2 v3 = *(const float2*)(p + 3 * PS);
    float sx = -2.0f * ((v0.x + v1.x) + (v2.x + v3.x));
    float sy = -2.0f * ((v0.y + v1.y) + (v2.y + v3.y));

    float m = fmaxf(sx, sy);
    #pragma unroll
    for (int off = 32; off; off >>= 1) m = fmaxf(m, __shfl_xor(m, off));
    int wave = tid >> 6;
    if ((tid & 63) == 0) red[wave] = m;
    __syncthreads();
    m = fmaxf(fmaxf(red[0], red[1]), fmaxf(red[2], red[3]));
    constexpr float L2E = 1.4426950408889634f;
    float e0 = __builtin_amdgcn_exp2f((sx - m) * L2E);
    float e1 = __builtin_amdgcn_exp2f((sy - m) * L2E);
    float s = e0 + e1;
    #pragma unroll
    for (int off = 32; off; off >>= 1) s += __shfl_xor(s, off);
    if ((tid & 63) == 0) red[4 + wave] = s;
    __syncthreads();
    float tot = (red[4] + red[5]) + (red[6] + red[7]);
    float inv = __builtin_amdgcn_rcpf(tot);
    float2 o; o.x = e0 * inv; o.y = e1 * inv;
    *(float2*)(attn + row * SEQ + tid * 2) = o;

    unsigned short h0 = bf16h(o.x), h1 = bf16h(o.y);
    unsigned hp = h0 | ((unsigned)h1 << 16);
    unsigned lp = bf16h(o.x - bf16f(h0)) | ((unsigned)bf16h(o.y - bf16f(h1)) << 16);
    *(unsigned*)&attn_h[row * SEQ + tid * 2] = hp;
    *(unsigned*)&attn_l[row * SEQ + tid * 2] = lp;
}

// ---------------------------------------------------------------------------
extern "C" void kernel_launch(void* const* d_in, const int* in_sizes, int n_in,
                              void* d_out, int out_size, void* d_ws, size_t ws_size,
                              hipStream_t stream) {
    const float* query = (const float*)d_in[0];
    const float* key   = (const float*)d_in[1];
    const float* value = (const float*)d_in[2];
    const float* Wq = (const float*)d_in[3];
    const float* bq = (const float*)d_in[4];
    const float* Wk = (const float*)d_in[5];
    const float* bk = (const float*)d_in[6];
    const float* Wv = (const float*)d_in[7];
    const float* bv = (const float*)d_in[8];
    const float* Ws = (const float*)d_in[9];
    // d_in[10] = bs: unused (softmax shift-invariance)
    const float* Wo = (const float*)d_in[11];
    const float* bo = (const float*)d_in[12];

    float* out  = (float*)d_out;                              // (4,512,256)
    float* attn = (float*)d_out + (long)BATCH * SEQ * DM;     // (4,1,512,512)

    float* ws = (float*)d_ws;
    float* Eq   = ws;                    // 524288 f32
    float* Ek   = ws + 524288;
    float* part = ws + 1048576;          // 4 x 1048576 f32 (d-chunk partials)
    float* att0 = part;                  // overlaid (part dead after softmax)
    float* att1 = part + 524288;
    ushort* u = (ushort*)(ws + 1048576 + 4194304);
    ushort* Wqh = u;              ushort* Wql = Wqh + 65536;
    ushort* Wkh = Wql + 65536;    ushort* Wkl = Wkh + 65536;
    ushort* Wvh = Wkl + 65536;    ushort* Wvl = Wvh + 65536;
    ushort* Woh = Wvl + 65536;    ushort* Wol = Woh + 65536;
    ushort* vpTh   = Wol + 65536;    ushort* vpTl   = vpTh + 524288;
    ushort* attn_h = vpTl + 524288;  ushort* attn_l = attn_h + 1048576;

    conv_w       <<<dim3(32, 4),    256, 0, stream>>>(Wq, Wk, Wv, Wo,
                                                      Wqh, Wql, Wkh, Wkl,
                                                      Wvh, Wvl, Woh, Wol);
    proj_mfma    <<<dim3(32, 4, 3), 256, 0, stream>>>(query, key, value,
                                                      Wqh, Wql, Wkh, Wkl, Wvh, Wvl,
                                                      bq, bk, bv, Eq, Ek, vpTh, vpTl);
    scores_kernel<<<dim3(8, 8, 16), 256, 0, stream>>>(Eq, Ek, Ws, part);
    softmax_kernel<<<dim3(2048),    256, 0, stream>>>(part, attn, attn_h, attn_l);
    attnv_mfma   <<<dim3(8, 4, 8),  256, 0, stream>>>(attn_h, attn_l, vpTh, vpTl, att0, att1);
    out_mfma     <<<dim3(32, 4),    256, 0, stream>>>(att0, att1, Woh, Wol, bo, out);
}